// Round 5
// baseline (1097.011 us; speedup 1.0000x reference)
//
#include <hip/hip_runtime.h>
#include <hip/hip_bf16.h>
#include <math.h>

// Transformer block on gfx950. bf16 MFMA GEMMs (16x16x32), fp32 accumulate.
// Round-5: BK=32 revert (m132: BK=64 regressed); cat eliminated -> per-group
// c_proj accumulation into y_f (split-K=2 partials in dead sc_g + accum);
// G=4 guaranteed / G=6 opportunistic; short4 softmax; fused bias+LN2;
// merged QKV weight transpose.

#define BM 128
#define BN 128
#define BK 32

typedef __attribute__((ext_vector_type(8))) short bf16x8;
typedef __attribute__((ext_vector_type(4))) float floatx4;

__device__ __forceinline__ short f2b(float f) {
  __hip_bfloat16 h = __float2bfloat16(f);
  return *reinterpret_cast<short*>(&h);
}
__device__ __forceinline__ float b2f(short s) {
  unsigned u = ((unsigned)(unsigned short)s) << 16;
  return __uint_as_float(u);
}

#if defined(__has_builtin)
#if __has_builtin(__builtin_amdgcn_global_load_lds)
#define HAS_GLLD 1
#endif
#endif

#ifdef HAS_GLLD
__device__ __forceinline__ void lds_dma16(const short* g, short* l) {
  __builtin_amdgcn_global_load_lds(
      (const __attribute__((address_space(1))) void*)g,
      (__attribute__((address_space(3))) void*)l, 16, 0, 0);
}
#endif

struct GP {
  const short* A; const short* B;
  long a_bs, b_bs;
  int lda, ldb;
  int a_kh; long a_hs;          // if a_kh>0: A addr = (k/a_kh)*a_hs + row*lda + k%a_kh
  const float* bias0; const float* bias1; const float* bias2;
  short* C0; short* C1; short* C2;
  float* Cf;
  int ldc, zmod;
  long cz0, cz1, c_zs;
  int K, kchunk;                // kchunk>0: z handles K range [z*kchunk, +kchunk)
  float alpha;
  int zoff;
};

// MODE 0: C0 = bf16(acc*alpha)            (CAUSAL=1 tile-skip; CAUSAL=2 K-limit)
// MODE 3: C0 = bf16(gelu(acc + bias0[col]))
// MODE 4: Cf[z*c_zs + ...] = acc          (split-K fp32 partial)
// MODE 5: QKV routing by column part: q->C0, k->C1, v->C2 (transposed layout)
template<int MODE, int CAUSAL>
__device__ __forceinline__ void gemm_body(const GP& p)
{
  int bx = blockIdx.x;
  if (CAUSAL == 2) bx = gridDim.x - 1 - bx;   // longest K first
  const int m0 = bx * BM, n0 = blockIdx.y * BN;
  if (CAUSAL == 1 && n0 > m0 + (BM - 1)) return;
  const int z = blockIdx.z;
  const short* Ab = p.A + (size_t)z * p.a_bs;
  const short* Bb = p.B + (size_t)z * p.b_bs;
  int kbeg = 0, kend = p.K;
  if (p.kchunk) { kbeg = z * p.kchunk; kend = kbeg + p.kchunk; }
  if (CAUSAL == 2) { int lim = m0 + BM; if (lim < kend) kend = lim; }

  // Row = 64 B (4 chunks of 16 B); chunk c of row r stored at pos (c + (r>>1)) & 3.
  // Measured 0 bank conflicts (round 3).
  __shared__ __align__(16) short As[BM * BK];
  __shared__ __align__(16) short Bs[BN * BK];

  const int tid = threadIdx.x;
  const int lane = tid & 63, wave = tid >> 6;
  const int wm = (wave >> 1) * 64, wn = (wave & 1) * 64;
  const int l15 = lane & 15, quad = lane >> 4;
  const int rl = lane >> 2, pl = lane & 3;

  floatx4 acc[4][4];
#pragma unroll
  for (int i = 0; i < 4; i++)
#pragma unroll
    for (int j = 0; j < 4; j++) acc[i][j] = (floatx4){0.f, 0.f, 0.f, 0.f};

  for (int k0 = kbeg; k0 < kend; k0 += BK) {
    const short* Ak = Ab; int kb = k0;
    if (p.a_kh) { int h = k0 / p.a_kh; Ak = Ab + (size_t)h * p.a_hs; kb = k0 - h * p.a_kh; }
#pragma unroll
    for (int s = 0; s < 2; s++) {
      const int win = wave * 2 + s;            // 8 windows of 16 rows (1 KB each)
      const int row = win * 16 + rl;
      const int cs = (pl - (row >> 1)) & 3;    // global chunk landing at LDS pos pl
      const short* ga = Ak + (size_t)(m0 + row) * p.lda + kb + cs * 8;
      const short* gb = Bb + (size_t)(n0 + row) * p.ldb + k0 + cs * 8;
#ifdef HAS_GLLD
      lds_dma16(ga, &As[win * 512]);
      lds_dma16(gb, &Bs[win * 512]);
#else
      *(int4*)&As[win * 512 + lane * 8] = *(const int4*)ga;
      *(int4*)&Bs[win * 512 + lane * 8] = *(const int4*)gb;
#endif
    }
    __syncthreads();
    bf16x8 fa[4], fb[4];
#pragma unroll
    for (int i = 0; i < 4; i++) {
      const int ra = wm + i * 16 + l15;
      fa[i] = *(const bf16x8*)&As[ra * 32 + ((quad + (ra >> 1)) & 3) * 8];
      const int rb = wn + i * 16 + l15;
      fb[i] = *(const bf16x8*)&Bs[rb * 32 + ((quad + (rb >> 1)) & 3) * 8];
    }
#pragma unroll
    for (int i = 0; i < 4; i++)
#pragma unroll
      for (int j = 0; j < 4; j++)
        acc[i][j] = __builtin_amdgcn_mfma_f32_16x16x32_bf16(fa[i], fb[j], acc[i][j], 0, 0, 0);
    __syncthreads();
  }

  // C/D layout (m89): col = lane&15, row = quad*4 + reg
  const long coff = (long)(z % p.zmod) * p.cz0 + (long)(z / p.zmod) * p.cz1;
#pragma unroll
  for (int j = 0; j < 4; j++) {
    const int col = n0 + wn + j * 16 + l15;
    if constexpr (MODE == 0) {
#pragma unroll
      for (int i = 0; i < 4; i++) {
        const int rb = m0 + wm + i * 16 + quad * 4;
#pragma unroll
        for (int r = 0; r < 4; r++)
          p.C0[coff + (size_t)(rb + r) * p.ldc + col] = f2b(acc[i][j][r] * p.alpha);
      }
    } else if constexpr (MODE == 5) {
      const int part = (n0 + wn) / 768;        // block-uniform: 0=q, 1=k, 2=v
      const int cc = col - part * 768;
      const float* bp_ = (part == 0) ? p.bias0 : ((part == 1) ? p.bias1 : p.bias2);
      const float bvv = bp_[(p.zoff + z) * 768 + cc];
      if (part < 2) {
        short* dst = part ? p.C1 : p.C0;
#pragma unroll
        for (int i = 0; i < 4; i++) {
          const int rb = m0 + wm + i * 16 + quad * 4;
#pragma unroll
          for (int r = 0; r < 4; r++)
            dst[(size_t)z * p.c_zs + (size_t)(rb + r) * 768 + cc] = f2b(acc[i][j][r] + bvv);
        }
      } else {
#pragma unroll
        for (int i = 0; i < 4; i++) {
          const int rb = m0 + wm + i * 16 + quad * 4;
          short4 pk;
          pk.x = f2b(acc[i][j][0] + bvv);
          pk.y = f2b(acc[i][j][1] + bvv);
          pk.z = f2b(acc[i][j][2] + bvv);
          pk.w = f2b(acc[i][j][3] + bvv);
          const size_t addr = (((size_t)z * 4 + (rb >> 10)) * 768 + cc) * 1024 + (rb & 1023);
          *(short4*)&p.C2[addr] = pk;
        }
      }
    } else if constexpr (MODE == 4) {
#pragma unroll
      for (int i = 0; i < 4; i++) {
        const int rb = m0 + wm + i * 16 + quad * 4;
#pragma unroll
        for (int r = 0; r < 4; r++)
          p.Cf[(size_t)z * p.c_zs + (size_t)(rb + r) * p.ldc + col] = acc[i][j][r];
      }
    } else {  // MODE 3: exact gelu
      const float bvv = p.bias0[col];
#pragma unroll
      for (int i = 0; i < 4; i++) {
        const int rb = m0 + wm + i * 16 + quad * 4;
#pragma unroll
        for (int r = 0; r < 4; r++) {
          float t = acc[i][j][r] + bvv;
          p.C0[(size_t)(rb + r) * p.ldc + col] = f2b(0.5f * t * (1.0f + erff(t * 0.70710678118654752440f)));
        }
      }
    }
  }
}

__global__ void __launch_bounds__(256) gemm_qkv(GP p)   { gemm_body<5, 0>(p); }
__global__ void __launch_bounds__(256) gemm_sco(GP p)   { gemm_body<0, 1>(p); }
__global__ void __launch_bounds__(256) gemm_pv(GP p)    { gemm_body<0, 2>(p); }
__global__ void __launch_bounds__(256) gemm_cproj(GP p) { gemm_body<4, 0>(p); }
__global__ void __launch_bounds__(256) gemm_fc(GP p)    { gemm_body<3, 0>(p); }
__global__ void __launch_bounds__(256) gemm_mproj(GP p) { gemm_body<4, 0>(p); }

// LN1: outf = LN(in)*g+b (fp32), outb = bf16(outf), y0 = outf (residual seed)
__global__ void __launch_bounds__(256) ln_kernel(
    const float* __restrict__ in, const float* __restrict__ g, const float* __restrict__ b,
    float* __restrict__ outf, short* __restrict__ outb, float* __restrict__ y0)
{
  const long r = blockIdx.x;
  const float* x = in + r * 768;
  const int tid = threadIdx.x;
  float v0 = x[tid], v1 = x[tid + 256], v2 = x[tid + 512];
  float s = v0 + v1 + v2;
  float sq = v0 * v0 + v1 * v1 + v2 * v2;
  __shared__ float red[8];
  int lane = tid & 63, wave = tid >> 6;
#pragma unroll
  for (int o = 1; o < 64; o <<= 1) { s += __shfl_xor(s, o); sq += __shfl_xor(sq, o); }
  if (lane == 0) { red[wave] = s; red[4 + wave] = sq; }
  __syncthreads();
  s = red[0] + red[1] + red[2] + red[3];
  sq = red[4] + red[5] + red[6] + red[7];
  float mean = s * (1.0f / 768.0f);
  float var = sq * (1.0f / 768.0f) - mean * mean;
  float inv = rsqrtf(var + 1e-5f);
#pragma unroll
  for (int u = 0; u < 3; u++) {
    int c = tid + u * 256;
    float v = (u == 0) ? v0 : ((u == 1) ? v1 : v2);
    float y = (v - mean) * inv * g[c] + b[c];
    outf[r * 768 + c] = y;
    outb[r * 768 + c] = f2b(y);
    y0[r * 768 + c] = y;
  }
}

// LN2: y = in + bias; outf = LN(y)*g+b, outb = bf16(outf)
__global__ void __launch_bounds__(256) ln2_kernel(
    const float* __restrict__ in, const float* __restrict__ bias,
    const float* __restrict__ g, const float* __restrict__ b,
    float* __restrict__ outf, short* __restrict__ outb)
{
  const long r = blockIdx.x;
  const int tid = threadIdx.x;
  float y[3];
#pragma unroll
  for (int u = 0; u < 3; u++) {
    const int c = tid + u * 256;
    y[u] = in[(size_t)r * 768 + c] + bias[c];
  }
  float s = y[0] + y[1] + y[2];
  float sq = y[0] * y[0] + y[1] * y[1] + y[2] * y[2];
  __shared__ float red[8];
  int lane = tid & 63, wave = tid >> 6;
#pragma unroll
  for (int o = 1; o < 64; o <<= 1) { s += __shfl_xor(s, o); sq += __shfl_xor(sq, o); }
  if (lane == 0) { red[wave] = s; red[4 + wave] = sq; }
  __syncthreads();
  s = red[0] + red[1] + red[2] + red[3];
  sq = red[4] + red[5] + red[6] + red[7];
  float mean = s * (1.0f / 768.0f);
  float var = sq * (1.0f / 768.0f) - mean * mean;
  float inv = rsqrtf(var + 1e-5f);
#pragma unroll
  for (int u = 0; u < 3; u++) {
    const int c = tid + u * 256;
    const float v = (y[u] - mean) * inv * g[c] + b[c];
    outf[(size_t)r * 768 + c] = v;
    outb[(size_t)r * 768 + c] = f2b(v);
  }
}

// Causal softmax, short4-vectorized, in place on bf16 scores [z][1024][1024].
__global__ void __launch_bounds__(256) softmax_kernel(short* __restrict__ sc)
{
  const long gr = blockIdx.x;
  const int i = (int)(gr & 1023);
  short* row = sc + (gr >> 10) * (1024L * 1024) + (long)i * 1024;
  const int L = i + 1;
  const int hi = i | 127;
  const int tid = threadIdx.x;
  const int lane = tid & 63, wave = tid >> 6;
  const int j0 = tid * 4;
  __shared__ float red[4];
  short4 p4 = *(const short4*)&row[j0];
  float v[4];
  v[0] = (j0 + 0 < L) ? b2f(p4.x) : -3.0e38f;
  v[1] = (j0 + 1 < L) ? b2f(p4.y) : -3.0e38f;
  v[2] = (j0 + 2 < L) ? b2f(p4.z) : -3.0e38f;
  v[3] = (j0 + 3 < L) ? b2f(p4.w) : -3.0e38f;
  float mx = fmaxf(fmaxf(v[0], v[1]), fmaxf(v[2], v[3]));
#pragma unroll
  for (int o = 1; o < 64; o <<= 1) mx = fmaxf(mx, __shfl_xor(mx, o));
  if (lane == 0) red[wave] = mx;
  __syncthreads();
  mx = fmaxf(fmaxf(red[0], red[1]), fmaxf(red[2], red[3]));
  __syncthreads();
  float sum = 0.0f;
#pragma unroll
  for (int t = 0; t < 4; t++)
    if (j0 + t < L) { v[t] = __expf(v[t] - mx); sum += v[t]; }
#pragma unroll
  for (int o = 1; o < 64; o <<= 1) sum += __shfl_xor(sum, o);
  if (lane == 0) red[wave] = sum;
  __syncthreads();
  sum = red[0] + red[1] + red[2] + red[3];
  float inv = 1.0f / sum;
  if (j0 <= hi) {   // store probs; zero the tail up to the 128-aligned PV K-limit
    short4 o4;
    o4.x = (j0 + 0 < L) ? f2b(v[0] * inv) : (short)0;
    o4.y = (j0 + 1 < L) ? f2b(v[1] * inv) : (short)0;
    o4.z = (j0 + 2 < L) ? f2b(v[2] * inv) : (short)0;
    o4.w = (j0 + 3 < L) ? f2b(v[3] * inv) : (short)0;
    *(short4*)&row[j0] = o4;
  }
}

// y += p0 (+ p1)
__global__ void __launch_bounds__(256) accum_kernel(
    float* __restrict__ y, const float* __restrict__ part, long pzs, int nsplit)
{
  const size_t idx = ((size_t)blockIdx.x * 256 + threadIdx.x) * 4;
  float4 a = *(const float4*)&y[idx];
  float4 b = *(const float4*)&part[idx];
  a.x += b.x; a.y += b.y; a.z += b.z; a.w += b.w;
  if (nsplit == 2) {
    float4 c = *(const float4*)&part[(size_t)pzs + idx];
    a.x += c.x; a.y += c.y; a.z += c.z; a.w += c.w;
  }
  *(float4*)&y[idx] = a;
}

// out = sum(partials) + bias + resid
__global__ void __launch_bounds__(256) reduce_kernel(
    const float* __restrict__ part, long pzs, int nsplit,
    const float* __restrict__ bias, const float* __restrict__ resid,
    float* __restrict__ out)
{
  const size_t idx = ((size_t)blockIdx.x * 256 + threadIdx.x) * 4;
  float4 s = *(const float4*)&part[idx];
  for (int zz = 1; zz < nsplit; zz++) {
    float4 q = *(const float4*)&part[(size_t)zz * pzs + idx];
    s.x += q.x; s.y += q.y; s.z += q.z; s.w += q.w;
  }
  const int c = (int)(idx % 768);
  float4 b = *(const float4*)&bias[c];
  float4 r = *(const float4*)&resid[idx];
  *(float4*)&out[idx] = make_float4(s.x + b.x + r.x, s.y + b.y + r.y,
                                    s.z + b.z + r.z, s.w + b.w + r.w);
}

// generic W[R][C] fp32 -> Wt[C][R] bf16
__global__ void __launch_bounds__(256) transpose_kernel(
    const float* __restrict__ W, short* __restrict__ Wt, int R, int C)
{
  __shared__ float tile[32][33];
  const int c0 = blockIdx.x * 32, r0 = blockIdx.y * 32;
  const int tx = threadIdx.x, ty = threadIdx.y;
#pragma unroll
  for (int i = 0; i < 32; i += 8)
    tile[ty + i][tx] = W[(size_t)(r0 + ty + i) * C + (c0 + tx)];
  __syncthreads();
#pragma unroll
  for (int i = 0; i < 32; i += 8)
    Wt[(size_t)(c0 + ty + i) * R + (r0 + tx)] = f2b(tile[tx][ty + i]);
}

// merged QKV weight transpose: z = h*3 + m; dst[h][m][768][768] = W_m[h]^T
__global__ void __launch_bounds__(256) transpose_qkv_kernel(
    const float* __restrict__ Wq, const float* __restrict__ Wk,
    const float* __restrict__ Wv, short* __restrict__ dst)
{
  __shared__ float tile[32][33];
  const int z = blockIdx.z, h = z / 3, m = z % 3;
  const float* W = ((m == 0) ? Wq : (m == 1) ? Wk : Wv) + (size_t)h * 768 * 768;
  short* out = dst + (size_t)z * 768 * 768;
  const int c0 = blockIdx.x * 32, r0 = blockIdx.y * 32;
  const int tx = threadIdx.x, ty = threadIdx.y;
#pragma unroll
  for (int i = 0; i < 32; i += 8)
    tile[ty + i][tx] = W[(size_t)(r0 + ty + i) * 768 + (c0 + tx)];
  __syncthreads();
#pragma unroll
  for (int i = 0; i < 32; i += 8)
    out[(size_t)(c0 + ty + i) * 768 + (r0 + tx)] = f2b(tile[tx][ty + i]);
}

extern "C" void kernel_launch(void* const* d_in, const int* in_sizes, int n_in,
                              void* d_out, int out_size, void* d_ws, size_t ws_size,
                              hipStream_t stream)
{
  (void)in_sizes; (void)n_in; (void)out_size;
  const float* inputs = (const float*)d_in[0];
  const float* g1  = (const float*)d_in[1];
  const float* b1  = (const float*)d_in[2];
  const float* Wq  = (const float*)d_in[3];
  const float* bq  = (const float*)d_in[4];
  const float* Wk  = (const float*)d_in[5];
  const float* bk  = (const float*)d_in[6];
  const float* Wv  = (const float*)d_in[7];
  const float* bv  = (const float*)d_in[8];
  const float* Wc  = (const float*)d_in[9];
  const float* bc  = (const float*)d_in[10];
  const float* g2  = (const float*)d_in[11];
  const float* b2  = (const float*)d_in[12];
  const float* Wfc = (const float*)d_in[13];
  const float* bfc = (const float*)d_in[14];
  const float* Wp  = (const float*)d_in[15];
  const float* bp  = (const float*)d_in[16];
  float* out = (float*)d_out;

  const size_t NS = 4096, E = 768, S = 1024;
  const size_t MB1 = NS * E * 2;     // 6.29 MB bf16 matrix
  const size_t MF1 = NS * E * 4;     // 12.58 MB fp32 matrix

  char* base = (char*)d_ws;
  size_t off = 0;
  auto alloc = [&](size_t n) { char* r = base + off; off = (off + n + 255) & ~(size_t)255; return r; };

  // ---- persistent (live whole launch): 83.4 MB ----
  float* x_f  = (float*)alloc(MF1);
  short* x_b  = (short*)alloc(MB1);
  short* Wqkv = (short*)alloc(36 * E * E * 2);   // [h][{q,k,v}][768][768] B^T bf16
  short* WcT  = (short*)alloc(E * 9216 * 2);
  short* WfcT = (short*)alloc(3072 * E * 2);
  short* WpT  = (short*)alloc(E * 3072 * 2);
  float* y_f  = (float*)alloc(MF1);              // attn residual accumulator

  // ---- overlay region R ----
  char* Rp = base + off;
  const size_t R_size = (ws_size > off) ? (ws_size - off) : 0;

  const size_t per_h = 4 * MB1 + 4 * S * S * 2;  // q+k+v+heads + scores = 32 MiB/head
  static const int Gs[5] = {6, 4, 3, 2, 1};      // divisors of 12 (balanced groups)
  int G = 1;
  for (int i = 0; i < 5; i++)
    if ((size_t)Gs[i] * per_h <= R_size) { G = Gs[i]; break; }

  short* q_g  = (short*)Rp;
  short* k_g  = q_g + (size_t)G * NS * E;
  short* vT_g = k_g + (size_t)G * NS * E;        // [z*4+n][768][1024]
  short* hd_g = vT_g + (size_t)G * NS * E;       // heads [G][4096][768]
  short* sc_g = hd_g + (size_t)G * NS * E;       // scores [4G][1024][1024]

  // c_proj partials: sc_g is dead by then (G>=3); for G<=2 alias q_g/k_g (also dead)
  const int csplit = (G == 1) ? 1 : 2;
  float* scp = (G >= 3) ? (float*)sc_g : (float*)q_g;

  // post-group overlay (whole attention pool dead)
  size_t o2 = 0;
  float* partB = (float*)(Rp + o2); o2 += 4 * MF1;
  float* y2_f  = (float*)(Rp + o2); o2 += MF1;
  short* y2_b  = (short*)(Rp + o2); o2 += MB1;
  short* h_b   = (short*)(Rp + o2); o2 += NS * 3072 * 2;

  const dim3 tb(32, 8);
  transpose_qkv_kernel<<<dim3(24, 24, 36), tb, 0, stream>>>(Wq, Wk, Wv, Wqkv);
  transpose_kernel<<<dim3(24, 288, 1), tb, 0, stream>>>(Wc, WcT, 9216, 768);
  transpose_kernel<<<dim3(96, 24, 1),  tb, 0, stream>>>(Wfc, WfcT, 768, 3072);
  transpose_kernel<<<dim3(24, 96, 1),  tb, 0, stream>>>(Wp, WpT, 3072, 768);

  ln_kernel<<<4096, 256, 0, stream>>>(inputs, g1, b1, x_f, x_b, y_f);

  const float sca = 0.03608439182435161f;  // 1/sqrt(768)
  for (int h0 = 0; h0 < 12; h0 += G) {
    {  // merged QKV: N = 2304 per head
      GP p{};
      p.A = x_b; p.lda = 768; p.a_bs = 0;
      p.B = Wqkv + (size_t)h0 * 3 * E * E; p.ldb = 768; p.b_bs = (long)(3 * E * E);
      p.bias0 = bq; p.bias1 = bk; p.bias2 = bv; p.zoff = h0;
      p.C0 = q_g; p.C1 = k_g; p.C2 = vT_g; p.c_zs = (long)(NS * E);
      p.ldc = 768; p.zmod = 1;
      p.K = 768; p.alpha = 1.0f;
      gemm_qkv<<<dim3(32, 18, G), 256, 0, stream>>>(p);
    }
    {  // scores = q k^T / sqrt(E), causal tile-skip
      GP p{};
      p.A = q_g; p.lda = 768; p.a_bs = (long)(S * E);
      p.B = k_g; p.ldb = 768; p.b_bs = (long)(S * E);
      p.C0 = sc_g; p.ldc = 1024; p.zmod = 1; p.cz0 = 0; p.cz1 = (long)(S * S);
      p.K = 768; p.alpha = sca;
      gemm_sco<<<dim3(8, 8, 4 * G), 256, 0, stream>>>(p);
    }
    softmax_kernel<<<4 * G * 1024, 256, 0, stream>>>(sc_g);
    {  // heads = attn @ v -> hd_g[g][4096][768]
      GP p{};
      p.A = sc_g; p.lda = 1024; p.a_bs = (long)(S * S);
      p.B = vT_g; p.ldb = 1024; p.b_bs = (long)(E * S);
      p.C0 = hd_g; p.ldc = 768;
      p.zmod = 4; p.cz0 = (long)(S * E); p.cz1 = (long)(NS * E);
      p.K = 1024; p.alpha = 1.0f;
      gemm_pv<<<dim3(8, 6, 4 * G), 256, 0, stream>>>(p);
    }
    {  // c_proj group partial: heads_g @ Wc[h0.. h0+G] (K = G*768, split csplit)
      GP p{};
      p.A = hd_g; p.lda = 768; p.a_kh = 768; p.a_hs = (long)(NS * E);
      p.B = WcT + (size_t)h0 * 768; p.ldb = 9216;
      p.Cf = scp; p.ldc = 768; p.c_zs = (long)(NS * E); p.zmod = 1;
      p.K = G * 768; p.kchunk = G * 768 / csplit; p.alpha = 1.0f;
      gemm_cproj<<<dim3(32, 6, csplit), 256, 0, stream>>>(p);
    }
    accum_kernel<<<3072, 256, 0, stream>>>(y_f, scp, (long)(NS * E), csplit);
  }

  // y2 = LN(y_f + bc)
  ln2_kernel<<<4096, 256, 0, stream>>>(y_f, bc, g2, b2, y2_f, y2_b);

  {  // fc + exact gelu
    GP p{};
    p.A = y2_b; p.lda = 768;
    p.B = WfcT; p.ldb = 768;
    p.bias0 = bfc; p.C0 = h_b; p.ldc = 3072; p.zmod = 1;
    p.K = 768; p.alpha = 1.0f;
    gemm_fc<<<dim3(32, 24, 1), 256, 0, stream>>>(p);
  }
  {  // proj split-K=4
    GP p{};
    p.A = h_b; p.lda = 3072;
    p.B = WpT; p.ldb = 3072;
    p.Cf = partB; p.ldc = 768; p.c_zs = (long)(NS * E); p.zmod = 1;
    p.K = 3072; p.kchunk = 768; p.alpha = 1.0f;
    gemm_mproj<<<dim3(32, 6, 4), 256, 0, stream>>>(p);
  }
  reduce_kernel<<<3072, 256, 0, stream>>>(partB, (long)(NS * E), 4, bp, y2_f, out);
}